// Round 10
// baseline (74.461 us; speedup 1.0000x reference)
//
#include <hip/hip_runtime.h>

#define BSZ  8
#define LSEQ 2048
#define DM   256
#define NS   16
#define NC   32          // chunks along L
#define LC   (LSEQ/NC)   // 64 timesteps per chunk
#define TILE_FLOATS (LC * DM)               // 64 KB LDS tile
#define VEC_ROUNDS  (TILE_FLOATS / 4 / DM)  // 16 float4 ops per thread

// Single-kernel decoupled lookback over chunk AGGREGATES.
//   A: stage x tile -> LDS (float4), local scan h0=0, publish aggregate+flag
//   B: spin for predecessor flags; Horner e = sum aL^(j-1-i) * c_i
//   C: seeded re-scan from LDS; y in place; float4 store
// 256 blocks on 256 CUs -> all co-resident -> spin-wait is deadlock-free.
// carry layout: [b][chunk][n][d]; flags [b][chunk], memset to 0 in-graph.
__global__ void k_fused(
        const float* __restrict__ x,
        const float* __restrict__ A,
        const float* __restrict__ Bm,
        const float* __restrict__ Cm,
        const float* __restrict__ Dv,
        const float* __restrict__ delta,
        float* __restrict__ carry,
        unsigned int* __restrict__ flags,
        float* __restrict__ y) {
    __shared__ float lx[TILE_FLOATS];
    const int d     = threadIdx.x;
    const int chunk = blockIdx.x & (NC - 1);
    const int b     = blockIdx.x / NC;

    const size_t tile_base = ((size_t)(b * LSEQ + chunk * LC)) * DM;
    {   // stage: 16 x (256 thr x 16 B) = 64 KB contiguous
        const float4* __restrict__ src = (const float4*)(x + tile_base);
        float4* dst = (float4*)lx;
#pragma unroll
        for (int r = 0; r < VEC_ROUNDS; ++r)
            dst[r * DM + d] = src[r * DM + d];
    }

    // coefficients overlap staging latency
    const float dt = 1.0f / (1.0f + expf(-delta[d]));
    float a[NS], bb[NS], cc[NS], aL[NS];
#pragma unroll
    for (int n = 0; n < NS; ++n) {
        const float An = A[d * NS + n];
        a[n]  = expf(dt * An);
        aL[n] = expf(dt * An * (float)LC);
        bb[n] = dt * Bm[d * NS + n];
        cc[n] = Cm[d * NS + n];
    }
    const float Dd = Dv[d];
    __syncthreads();

    // ---- phase A: local aggregate (h0 = 0) ----
    float h[NS];
#pragma unroll
    for (int n = 0; n < NS; ++n) h[n] = 0.0f;
#pragma unroll 4
    for (int t = 0; t < LC; ++t) {
        const float xv = lx[t * DM + d];
#pragma unroll
        for (int n = 0; n < NS; ++n) h[n] = fmaf(a[n], h[n], bb[n] * xv);
    }

    if (chunk < NC - 1) {   // last chunk's aggregate is never consumed
        float* cp = carry + ((size_t)(b * NC + chunk) * NS) * DM + d;
#pragma unroll
        for (int n = 0; n < NS; ++n) cp[(size_t)n * DM] = h[n];
        __threadfence();                 // each thread's stores visible device-wide
        __syncthreads();                 // all threads' fences done
        if (threadIdx.x == 0)
            __hip_atomic_store(&flags[b * NC + chunk], 1u,
                               __ATOMIC_RELEASE, __HIP_MEMORY_SCOPE_AGENT);
    }

    // ---- phase B: lookback over predecessor aggregates ----
#pragma unroll
    for (int n = 0; n < NS; ++n) h[n] = 0.0f;   // h becomes the entry state
    if (chunk > 0) {                            // block-uniform branch
        if (d < chunk) {
            while (__hip_atomic_load(&flags[b * NC + d],
                                     __ATOMIC_ACQUIRE,
                                     __HIP_MEMORY_SCOPE_AGENT) != 1u) {}
        }
        __syncthreads();
        const float* cb = carry + ((size_t)b * NC * NS) * DM + d;
#pragma unroll 2
        for (int i = 0; i < chunk; ++i) {
            const float* ci = cb + (size_t)i * NS * DM;
#pragma unroll
            for (int n = 0; n < NS; ++n)
                h[n] = fmaf(aL[n], h[n], ci[(size_t)n * DM]);
        }
    }

    // ---- phase C: seeded scan from LDS; y in place; vector store ----
#pragma unroll 4
    for (int t = 0; t < LC; ++t) {
        const float xv = lx[t * DM + d];
        float acc = Dd * xv;
#pragma unroll
        for (int n = 0; n < NS; ++n) {
            h[n] = fmaf(a[n], h[n], bb[n] * xv);
            acc  = fmaf(h[n], cc[n], acc);
        }
        lx[t * DM + d] = acc;    // column d owned by thread d: no hazard
    }
    __syncthreads();
    {
        float4* __restrict__ dst = (float4*)(y + tile_base);
        const float4* src = (const float4*)lx;
#pragma unroll
        for (int r = 0; r < VEC_ROUNDS; ++r)
            dst[r * DM + d] = src[r * DM + d];
    }
}

// ---------------------------------------------------------------------------
extern "C" void kernel_launch(void* const* d_in, const int* in_sizes, int n_in,
                              void* d_out, int out_size, void* d_ws, size_t ws_size,
                              hipStream_t stream) {
    const float* x     = (const float*)d_in[0];
    const float* A     = (const float*)d_in[1];
    const float* Bm    = (const float*)d_in[2];
    const float* Cm    = (const float*)d_in[3];
    const float* Dv    = (const float*)d_in[4];
    const float* delta = (const float*)d_in[5];
    float* y = (float*)d_out;

    const size_t carry_bytes = (size_t)BSZ * NC * NS * DM * sizeof(float); // 4 MiB
    float*        carry = (float*)d_ws;
    unsigned int* flags = (unsigned int*)((char*)d_ws + carry_bytes);      // 1 KiB

    hipMemsetAsync(flags, 0, BSZ * NC * sizeof(unsigned int), stream);
    k_fused<<<dim3(BSZ * NC), dim3(DM), 0, stream>>>(
        x, A, Bm, Cm, Dv, delta, carry, flags, y);
}

// Round 11
// 35.010 us; speedup vs baseline: 2.1268x; 2.1268x over previous
//
#include <hip/hip_runtime.h>

#define BSZ  8
#define LSEQ 2048
#define DM   256
#define NS   16
#define NC   32          // chunks along L
#define LC   (LSEQ/NC)   // 64 timesteps per chunk
#define TILE_FLOATS (LC * DM)               // 64 KB LDS tile
#define VEC_ROUNDS  (TILE_FLOATS / 4 / DM)  // 16 float4 ops per thread

// ---------------------------------------------------------------------------
// Kernel 1: per-(b,chunk) local scan, h0=0; emit carry aggregate.
// r9 body: float4 -> LDS staging (contiguous 64 KB), scan from LDS.
// carry layout: [b][chunk][n][d]  (d contiguous -> coalesced)
// ---------------------------------------------------------------------------
__global__ void k_local(
        const float* __restrict__ x,
        const float* __restrict__ A,
        const float* __restrict__ Bm,
        const float* __restrict__ delta,
        float* __restrict__ carry) {
    __shared__ float lx[TILE_FLOATS];
    const int d     = threadIdx.x;
    const int chunk = blockIdx.x & (NC - 1);
    const int b     = blockIdx.x / NC;

    {   // vectorized stage: 16 rounds x 256 thr x 16 B = 64 KB
        const float4* __restrict__ src =
            (const float4*)(x + ((size_t)(b * LSEQ + chunk * LC)) * DM);
        float4* dst = (float4*)lx;
#pragma unroll
        for (int r = 0; r < VEC_ROUNDS; ++r)
            dst[r * DM + d] = src[r * DM + d];
    }

    const float dt = 1.0f / (1.0f + expf(-delta[d]));
    float a[NS], bb[NS];
#pragma unroll
    for (int n = 0; n < NS; ++n) {
        a[n]  = expf(dt * A[d * NS + n]);
        bb[n] = dt * Bm[d * NS + n];
    }
    __syncthreads();

    float h[NS];
#pragma unroll
    for (int n = 0; n < NS; ++n) h[n] = 0.0f;
#pragma unroll 4
    for (int t = 0; t < LC; ++t) {
        const float xv = lx[t * DM + d];
#pragma unroll
        for (int n = 0; n < NS; ++n) h[n] = fmaf(a[n], h[n], bb[n] * xv);
    }

    float* cp = carry + ((size_t)(b * NC + chunk) * NS) * DM + d;
#pragma unroll
    for (int n = 0; n < NS; ++n) cp[(size_t)n * DM] = h[n];
}

// ---------------------------------------------------------------------------
// Kernel 2: fused prefix + final scan.  Each (b,chunk=j) block computes its
// entry state from carries of chunks 0..j-1 via Horner:
//   h_entry = sum_{i<j} aL^(j-1-i) * c_i,   aL = exp(dt*A*LC)
// At NC=32 this is <=31 rounds of 16 coalesced L2/L3-resident loads
// (63 MB aggregate -- 1/4 of round-8's NC=64 cost, which was the regression).
// Kernel boundary provides carry visibility: no fences, no flags (r10 lesson:
// in-kernel device-scope sync cost ~45 us).
// Then seeded scan from the LDS x tile; y in place; float4 store.
// ---------------------------------------------------------------------------
__global__ void k_final(
        const float* __restrict__ x,
        const float* __restrict__ A,
        const float* __restrict__ Bm,
        const float* __restrict__ Cm,
        const float* __restrict__ Dv,
        const float* __restrict__ delta,
        const float* __restrict__ carry,
        float* __restrict__ y) {
    __shared__ float lt[TILE_FLOATS];
    const int d     = threadIdx.x;
    const int chunk = blockIdx.x & (NC - 1);
    const int b     = blockIdx.x / NC;

    const size_t tile_base = ((size_t)(b * LSEQ + chunk * LC)) * DM;
    {   // vectorized stage of x tile (overlaps with Horner's carry loads)
        const float4* __restrict__ src = (const float4*)(x + tile_base);
        float4* dst = (float4*)lt;
#pragma unroll
        for (int r = 0; r < VEC_ROUNDS; ++r)
            dst[r * DM + d] = src[r * DM + d];
    }

    const float dt = 1.0f / (1.0f + expf(-delta[d]));
    float a[NS], bb[NS], cc[NS], aL[NS];
#pragma unroll
    for (int n = 0; n < NS; ++n) {
        const float An = A[d * NS + n];
        a[n]  = expf(dt * An);
        aL[n] = expf(dt * An * (float)LC);
        bb[n] = dt * Bm[d * NS + n];
        cc[n] = Cm[d * NS + n];
    }
    const float Dd = Dv[d];

    // entry state via Horner over predecessor aggregates
    float h[NS];
#pragma unroll
    for (int n = 0; n < NS; ++n) h[n] = 0.0f;
    {
        const float* cb = carry + ((size_t)b * NC * NS) * DM + d;
#pragma unroll 2
        for (int i = 0; i < chunk; ++i) {
            const float* ci = cb + (size_t)i * NS * DM;
#pragma unroll
            for (int n = 0; n < NS; ++n)
                h[n] = fmaf(aL[n], h[n], ci[(size_t)n * DM]);
        }
    }
    __syncthreads();

    // seeded scan; y computed in place in LDS; vector store
#pragma unroll 4
    for (int t = 0; t < LC; ++t) {
        const float xv = lt[t * DM + d];
        float acc = Dd * xv;
#pragma unroll
        for (int n = 0; n < NS; ++n) {
            h[n] = fmaf(a[n], h[n], bb[n] * xv);
            acc  = fmaf(h[n], cc[n], acc);
        }
        lt[t * DM + d] = acc;    // slot (t,d) owned by thread d
    }
    __syncthreads();
    {
        float4* __restrict__ dst = (float4*)(y + tile_base);
        const float4* src = (const float4*)lt;
#pragma unroll
        for (int r = 0; r < VEC_ROUNDS; ++r)
            dst[r * DM + d] = src[r * DM + d];
    }
}

// ---------------------------------------------------------------------------
extern "C" void kernel_launch(void* const* d_in, const int* in_sizes, int n_in,
                              void* d_out, int out_size, void* d_ws, size_t ws_size,
                              hipStream_t stream) {
    const float* x     = (const float*)d_in[0];
    const float* A     = (const float*)d_in[1];
    const float* Bm    = (const float*)d_in[2];
    const float* Cm    = (const float*)d_in[3];
    const float* Dv    = (const float*)d_in[4];
    const float* delta = (const float*)d_in[5];
    float* y = (float*)d_out;

    float* carry = (float*)d_ws;   // BSZ*NC*NS*DM*4 = 4.2 MiB scratch

    dim3 blk(DM);
    dim3 grd(BSZ * NC);                  // 256 blocks
    k_local<<<grd, blk, 0, stream>>>(x, A, Bm, delta, carry);
    k_final<<<grd, blk, 0, stream>>>(x, A, Bm, Cm, Dv, delta, carry, y);
}